// Round 2
// baseline (436.198 us; speedup 1.0000x reference)
//
#include <hip/hip_runtime.h>
#include <math.h>

#define BINS 2048
#define UPSAMPLE 128

// Order-preserving encode of float into unsigned so atomicMin/atomicMax work.
__device__ __forceinline__ unsigned enc_f32(float f) {
    unsigned u = __float_as_uint(f);
    return (u & 0x80000000u) ? ~u : (u | 0x80000000u);
}
__device__ __forceinline__ float dec_f32(unsigned e) {
    unsigned u = (e & 0x80000000u) ? (e ^ 0x80000000u) : ~e;
    return __uint_as_float(u);
}

// out[0..2047]   : histogram accumulator (float)
// out[2048..2049]: encoded running min/max (as unsigned) during passes; final cmin/cmax
__global__ void hq_init(float* out) {
    int i = blockIdx.x * blockDim.x + threadIdx.x;
    if (i < BINS) out[i] = 0.0f;
    if (i == BINS)     ((unsigned*)out)[BINS]     = 0xFFFFFFFFu; // +inf-ish for min
    if (i == BINS + 1) ((unsigned*)out)[BINS + 1] = 0u;          // -inf-ish for max
}

__global__ void __launch_bounds__(256) hq_minmax(const float4* __restrict__ x4, long n4,
                                                 const float* __restrict__ xt, int ntail,
                                                 unsigned* mm) {
    float vmin = INFINITY, vmax = -INFINITY;
    long i0 = (long)blockIdx.x * blockDim.x + threadIdx.x;
    long stride = (long)gridDim.x * blockDim.x;
    for (long i = i0; i < n4; i += stride) {
        float4 v = x4[i];
        vmin = fminf(vmin, fminf(fminf(v.x, v.y), fminf(v.z, v.w)));
        vmax = fmaxf(vmax, fmaxf(fmaxf(v.x, v.y), fmaxf(v.z, v.w)));
    }
    if (blockIdx.x == 0 && threadIdx.x < ntail) {
        float xv = xt[threadIdx.x];
        vmin = fminf(vmin, xv);
        vmax = fmaxf(vmax, xv);
    }
    #pragma unroll
    for (int off = 32; off; off >>= 1) {
        vmin = fminf(vmin, __shfl_xor(vmin, off));
        vmax = fmaxf(vmax, __shfl_xor(vmax, off));
    }
    __shared__ float smin[4], smax[4];
    int wid = threadIdx.x >> 6, lane = threadIdx.x & 63;
    if (lane == 0) { smin[wid] = vmin; smax[wid] = vmax; }
    __syncthreads();
    if (threadIdx.x == 0) {
        float bmin = fminf(fminf(smin[0], smin[1]), fminf(smin[2], smin[3]));
        float bmax = fmaxf(fmaxf(smax[0], smax[1]), fmaxf(smax[2], smax[3]));
        atomicMin(&mm[0], enc_f32(bmin));
        atomicMax(&mm[1], enc_f32(bmax));
    }
}

__device__ __forceinline__ void hist_bin_add(float xv, float hmn, float hmx, float range,
                                             unsigned* sh) {
    if (xv >= hmn && xv <= hmx) {
        float rel = (xv - hmn) / range;                       // IEEE div, matches ref
        int idx = (int)fminf(fmaxf(floorf(rel * (float)BINS), 0.0f), (float)(BINS - 1));
        atomicAdd(&sh[idx], 1u);
    }
}

__global__ void __launch_bounds__(1024) hq_hist(const float4* __restrict__ x4, long n4,
                                                const float* __restrict__ xt, int ntail,
                                                float* __restrict__ out,
                                                const float* __restrict__ min_val,
                                                const float* __restrict__ max_val) {
    __shared__ unsigned sh[BINS];
    for (int i = threadIdx.x; i < BINS; i += blockDim.x) sh[i] = 0u;

    const unsigned* mm = (const unsigned*)(out + BINS);
    float mn = min_val[0], mx = max_val[0];
    float cmin  = fminf(dec_f32(mm[0]), mn);
    float cmax0 = fmaxf(dec_f32(mm[1]), mx);
    float hbw = (mx - mn) / (float)(BINS * UPSAMPLE);
    float bw  = (float)BINS * hbw;
    float dr_f = ceilf((cmax0 - cmin) / bw);
    float cmax = cmax0 + (dr_f * bw - (cmax0 - cmin));
    float hmn = truncf(cmin), hmx = truncf(cmax);
    float range = hmx - hmn;
    __syncthreads();

    long i0 = (long)blockIdx.x * blockDim.x + threadIdx.x;
    long stride = (long)gridDim.x * blockDim.x;
    for (long i = i0; i < n4; i += stride) {
        float4 v = x4[i];
        hist_bin_add(v.x, hmn, hmx, range, sh);
        hist_bin_add(v.y, hmn, hmx, range, sh);
        hist_bin_add(v.z, hmn, hmx, range, sh);
        hist_bin_add(v.w, hmn, hmx, range, sh);
    }
    if (blockIdx.x == 0 && threadIdx.x < ntail) {
        hist_bin_add(xt[threadIdx.x], hmn, hmx, range, sh);
    }
    __syncthreads();
    for (int i = threadIdx.x; i < BINS; i += blockDim.x) {
        unsigned c = sh[i];
        if (c) atomicAdd(&out[i], (float)c);
    }
}

__global__ void __launch_bounds__(1024) hq_finalize(float* __restrict__ out,
                                                    const float* __restrict__ old_hist,
                                                    const float* __restrict__ min_val,
                                                    const float* __restrict__ max_val) {
    __shared__ float h[BINS];
    __shared__ float sc[2][BINS];
    int t = threadIdx.x;  // 1024 threads, 2 bins each

    const unsigned* mm = (const unsigned*)(out + BINS);
    unsigned emin = mm[0], emax = mm[1];   // read BEFORE the final overwrite
    float mn = min_val[0], mx = max_val[0];

    h[t]        = old_hist[t];
    h[t + 1024] = old_hist[t + 1024];
    sc[0][t]        = h[t];
    sc[0][t + 1024] = h[t + 1024];
    __syncthreads();

    // Hillis-Steele inclusive scan over 2048 elements (11 passes, dbuf)
    int src = 0;
    for (int off = 1; off < BINS; off <<= 1) {
        int dst = src ^ 1;
        #pragma unroll
        for (int k = 0; k < 2; ++k) {
            int i = t + k * 1024;
            float v = sc[src][i];
            if (i >= off) v += sc[src][i - off];
            sc[dst][i] = v;
        }
        __syncthreads();
        src = dst;
    }
    const float* incl = sc[src];

    float cmin  = fminf(dec_f32(emin), mn);
    float cmax0 = fmaxf(dec_f32(emax), mx);
    float hbw = (mx - mn) / (float)(BINS * UPSAMPLE);
    float bw  = (float)BINS * hbw;
    float dr_f = ceilf((cmax0 - cmin) / bw);
    float cmax = cmax0 + (dr_f * bw - (cmax0 - cmin));
    int dr = (int)dr_f;
    int start_idx = (int)rintf((mn - cmin) / hbw);  // rintf = round-half-even, matches jnp.round
    bool same = (cmin == mn) && (cmax == mx);

    #pragma unroll
    for (int k = 0; k < 2; ++k) {
        int i = t + k * 1024;
        float integ_i = 0.0f, integ_p = 0.0f;
        {
            int q = (i + 1) * dr - 1 - start_idx;
            if (q >= 0) {
                int qc = min(q, BINS * UPSAMPLE - 1);
                int j = qc >> 7;
                float pref = (j ? incl[j - 1] : 0.0f) * (float)UPSAMPLE;
                integ_i = pref + ((float)(qc & 127) + 1.0f) * h[j];
            }
        }
        if (i > 0) {
            int q = i * dr - 1 - start_idx;
            if (q >= 0) {
                int qc = min(q, BINS * UPSAMPLE - 1);
                int j = qc >> 7;
                float pref = (j ? incl[j - 1] : 0.0f) * (float)UPSAMPLE;
                integ_p = pref + ((float)(qc & 127) + 1.0f) * h[j];
            }
        }
        float interp = (integ_i - integ_p) * (1.0f / (float)UPSAMPLE);
        out[i] = out[i] + (same ? h[i] : interp);
    }
    if (t == 0) {
        out[BINS]     = cmin;
        out[BINS + 1] = cmax;
    }
}

extern "C" void kernel_launch(void* const* d_in, const int* in_sizes, int n_in,
                              void* d_out, int out_size, void* d_ws, size_t ws_size,
                              hipStream_t stream) {
    (void)d_ws; (void)ws_size; (void)n_in; (void)out_size;
    const float* x         = (const float*)d_in[0];
    const float* histogram = (const float*)d_in[1];
    const float* min_val   = (const float*)d_in[2];
    const float* max_val   = (const float*)d_in[3];
    float* out = (float*)d_out;

    long n  = (long)in_sizes[0];
    long n4 = n >> 2;
    int ntail = (int)(n & 3);
    const float* xt = x + (n4 << 2);

    hq_init<<<(BINS + 2 + 255) / 256, 256, 0, stream>>>(out);
    hq_minmax<<<2048, 256, 0, stream>>>((const float4*)x, n4, xt, ntail,
                                        (unsigned*)(out + BINS));
    hq_hist<<<512, 1024, 0, stream>>>((const float4*)x, n4, xt, ntail, out,
                                      min_val, max_val);
    hq_finalize<<<1, 1024, 0, stream>>>(out, histogram, min_val, max_val);
}

// Round 3
// 387.730 us; speedup vs baseline: 1.1250x; 1.1250x over previous
//
#include <hip/hip_runtime.h>
#include <math.h>

#define BINS 2048
#define UPSAMPLE 128

// Fine grid: width 1/2048. All final bin edges hmn + k*(hmx-hmn)/2048 have
// INTEGER hmn/hmx, so every edge is an integer multiple of 1/2048 -> a fixed
// fine histogram built before min/max is known can be coarsened exactly.
#define LWIN 16384              // LDS window bins, covers [-4, 4)
#define LHALF 8192
#define WIDE_N 4194304          // wide grid bins, covers [-1024, 1024)
#define WIDE_HALF 2097152
#define NBLK 512                // pass-1 blocks
#define RGROUPS 8               // reduce: partials split into 8 groups of 64

// d_ws layout (uint32 units):
//   [0, WIDE_N)                 wide fine grid
//   [WIDE_N], [WIDE_N+1]        encoded running min / max
//   [PART_OFF, +NBLK*LWIN)      per-block partial fine hists
#define MM_OFF   WIDE_N
#define PART_OFF (WIDE_N + 16)

__device__ __forceinline__ unsigned enc_f32(float f) {
    unsigned u = __float_as_uint(f);
    return (u & 0x80000000u) ? ~u : (u | 0x80000000u);
}
__device__ __forceinline__ float dec_f32(unsigned e) {
    unsigned u = (e & 0x80000000u) ? (e ^ 0x80000000u) : ~e;
    return __uint_as_float(u);
}

__global__ void __launch_bounds__(256) hq_init(unsigned* ws) {
    long i = (long)blockIdx.x * blockDim.x + threadIdx.x;   // 1048576 threads
    ((uint4*)ws)[i] = make_uint4(0u, 0u, 0u, 0u);           // zero wide grid
    if (i == 0) {
        ws[MM_OFF]     = 0xFFFFFFFFu;  // min sentinel (encoded +inf side)
        ws[MM_OFF + 1] = 0u;           // max sentinel
    }
}

__device__ __forceinline__ void fine_add(float c, float& vmin, float& vmax,
                                         unsigned* sh, unsigned* ws) {
    vmin = fminf(vmin, c);
    vmax = fmaxf(vmax, c);
    float t = floorf(c * 2048.0f);                 // EXACT: pow2 multiply
    t = fminf(fmaxf(t, -2097152.0f), 2097151.0f);  // clamp into wide grid
    int fi = (int)t;
    int li = fi + LHALF;
    if ((unsigned)li < (unsigned)LWIN) {
        atomicAdd(&sh[li], 1u);                    // common path: LDS
    } else {
        atomicAdd(&ws[fi + WIDE_HALF], 1u);        // rare: |x| >= 4
    }
}

__global__ void __launch_bounds__(1024) hq_pass1(const float4* __restrict__ x4, long n4,
                                                 const float* __restrict__ xt, int ntail,
                                                 unsigned* __restrict__ ws) {
    __shared__ unsigned sh[LWIN];
    __shared__ float smin[16], smax[16];
    for (int i = threadIdx.x; i < LWIN; i += 1024) sh[i] = 0u;
    __syncthreads();

    float vmin = INFINITY, vmax = -INFINITY;
    long i0 = (long)blockIdx.x * blockDim.x + threadIdx.x;
    long stride = (long)gridDim.x * blockDim.x;
    for (long i = i0; i < n4; i += stride) {
        float4 v = x4[i];
        fine_add(v.x, vmin, vmax, sh, ws);
        fine_add(v.y, vmin, vmax, sh, ws);
        fine_add(v.z, vmin, vmax, sh, ws);
        fine_add(v.w, vmin, vmax, sh, ws);
    }
    if (blockIdx.x == 0 && threadIdx.x < ntail) {
        fine_add(xt[threadIdx.x], vmin, vmax, sh, ws);
    }

    #pragma unroll
    for (int off = 32; off; off >>= 1) {
        vmin = fminf(vmin, __shfl_xor(vmin, off));
        vmax = fmaxf(vmax, __shfl_xor(vmax, off));
    }
    int wid = threadIdx.x >> 6, lane = threadIdx.x & 63;
    if (lane == 0) { smin[wid] = vmin; smax[wid] = vmax; }
    __syncthreads();   // also fences all LDS hist atomics

    if (threadIdx.x == 0) {
        float bmin = INFINITY, bmax = -INFINITY;
        #pragma unroll
        for (int w = 0; w < 16; ++w) {
            bmin = fminf(bmin, smin[w]);
            bmax = fmaxf(bmax, smax[w]);
        }
        atomicMin(&ws[MM_OFF], enc_f32(bmin));
        atomicMax(&ws[MM_OFF + 1], enc_f32(bmax));
    }

    unsigned* part = ws + PART_OFF + (size_t)blockIdx.x * LWIN;
    for (int i = threadIdx.x; i < LWIN; i += 1024) part[i] = sh[i];
}

// Sum the NBLK partials per fine bin and merge into the wide grid.
// grid = 512 blocks x 256: block -> (bin chunk c of 256 bins, partial group g of 64)
__global__ void __launch_bounds__(256) hq_reduce(unsigned* __restrict__ ws) {
    int c = blockIdx.x & 63;          // 64 chunks of 256 bins = 16384
    int g = blockIdx.x >> 6;          // 8 groups of 64 partials
    int bin = c * 256 + threadIdx.x;
    const unsigned* p = ws + PART_OFF + bin + (size_t)g * 64 * LWIN;
    unsigned s = 0;
    #pragma unroll 8
    for (int b = 0; b < 64; ++b) s += p[(size_t)b * LWIN];
    if (s) atomicAdd(&ws[bin + (WIDE_HALF - LHALF)], s);
}

__global__ void __launch_bounds__(1024) hq_finalize(float* __restrict__ out,
                                                    const float* __restrict__ old_hist,
                                                    const float* __restrict__ min_val,
                                                    const float* __restrict__ max_val,
                                                    const unsigned* __restrict__ ws) {
    __shared__ float h[BINS];
    __shared__ float sc[2][BINS];
    int t = threadIdx.x;  // 1024 threads, 2 bins each

    float mn = min_val[0], mx = max_val[0];
    float cmin  = fminf(dec_f32(ws[MM_OFF]), mn);
    float cmax0 = fmaxf(dec_f32(ws[MM_OFF + 1]), mx);

    h[t]        = old_hist[t];
    h[t + 1024] = old_hist[t + 1024];
    sc[0][t]        = h[t];
    sc[0][t + 1024] = h[t + 1024];
    __syncthreads();

    // Hillis-Steele inclusive scan over 2048 elements
    int src = 0;
    for (int off = 1; off < BINS; off <<= 1) {
        int dst = src ^ 1;
        #pragma unroll
        for (int k = 0; k < 2; ++k) {
            int i = t + k * 1024;
            float v = sc[src][i];
            if (i >= off) v += sc[src][i - off];
            sc[dst][i] = v;
        }
        __syncthreads();
        src = dst;
    }
    const float* incl = sc[src];

    float hbw = (mx - mn) / (float)(BINS * UPSAMPLE);
    float bw  = (float)BINS * hbw;
    float dr_f = ceilf((cmax0 - cmin) / bw);
    float cmax = cmax0 + (dr_f * bw - (cmax0 - cmin));
    float hmn = truncf(cmin), hmx = truncf(cmax);   // integer-valued
    int dr = (int)dr_f;
    int start_idx = (int)rintf((mn - cmin) / hbw);  // round-half-even = jnp.round
    bool same = (cmin == mn) && (cmax == mx);
    int hmn_i = (int)hmn;
    int range_i = (int)(hmx - hmn);

    #pragma unroll
    for (int k = 0; k < 2; ++k) {
        int i = t + k * 1024;

        // hist_new[i]: sum of range_i fine bins starting at fine edge
        float hn = 0.0f;
        if (range_i > 0) {
            long fi0 = (long)hmn_i * 2048 + (long)i * range_i + WIDE_HALF;
            unsigned s = 0;
            for (int r = 0; r < range_i; ++r) {
                long fi = fi0 + r;
                if (fi >= 0 && fi < (long)WIDE_N) s += ws[fi];
            }
            hn = (float)s;
        }

        // analytic combine of the old histogram (unchanged from passing r2)
        float integ_i = 0.0f, integ_p = 0.0f;
        {
            int q = (i + 1) * dr - 1 - start_idx;
            if (q >= 0) {
                int qc = min(q, BINS * UPSAMPLE - 1);
                int j = qc >> 7;
                float pref = (j ? incl[j - 1] : 0.0f) * (float)UPSAMPLE;
                integ_i = pref + ((float)(qc & 127) + 1.0f) * h[j];
            }
        }
        if (i > 0) {
            int q = i * dr - 1 - start_idx;
            if (q >= 0) {
                int qc = min(q, BINS * UPSAMPLE - 1);
                int j = qc >> 7;
                float pref = (j ? incl[j - 1] : 0.0f) * (float)UPSAMPLE;
                integ_p = pref + ((float)(qc & 127) + 1.0f) * h[j];
            }
        }
        float interp = (integ_i - integ_p) * (1.0f / (float)UPSAMPLE);
        out[i] = hn + (same ? h[i] : interp);
    }
    if (t == 0) {
        out[BINS]     = cmin;
        out[BINS + 1] = cmax;
    }
}

extern "C" void kernel_launch(void* const* d_in, const int* in_sizes, int n_in,
                              void* d_out, int out_size, void* d_ws, size_t ws_size,
                              hipStream_t stream) {
    (void)n_in; (void)out_size; (void)ws_size;
    const float* x         = (const float*)d_in[0];
    const float* histogram = (const float*)d_in[1];
    const float* min_val   = (const float*)d_in[2];
    const float* max_val   = (const float*)d_in[3];
    float* out   = (float*)d_out;
    unsigned* ws = (unsigned*)d_ws;

    long n  = (long)in_sizes[0];
    long n4 = n >> 2;
    int ntail = (int)(n & 3);
    const float* xt = x + (n4 << 2);

    hq_init<<<WIDE_N / 4 / 256, 256, 0, stream>>>(ws);
    hq_pass1<<<NBLK, 1024, 0, stream>>>((const float4*)x, n4, xt, ntail, ws);
    hq_reduce<<<64 * RGROUPS, 256, 0, stream>>>(ws);
    hq_finalize<<<1, 1024, 0, stream>>>(out, histogram, min_val, max_val, ws);
}

// Round 6
// 371.301 us; speedup vs baseline: 1.1748x; 1.0442x over previous
//
#include <hip/hip_runtime.h>
#include <math.h>

#define BINS 2048
#define UPSAMPLE 128

// Fine grid: width 1/2048. histc range endpoints trunc(cmin)/trunc(cmax) are
// INTEGERS, so every final bin edge is an integer multiple of 1/2048 -> a
// fixed fine histogram (built before min/max is known) coarsens exactly.
#define LWIN 16384              // fine bins covered by LDS window: [-4, 4)
#define LHALF 8192
#define LWORDS 8192             // packed: 2 x u16 counters per u32 word
#define WIDE_N 4194304          // wide grid bins, covers [-1024, 1024)
#define WIDE_HALF 2097152
#define NBLK 1024               // pass-1 blocks (4 per CU)
#define NTHR 512
#define RGRP 32                 // reduce: 32 partials per group, 32 groups

// d_ws layout (uint32 units):
//   [0, WIDE_N)                 wide fine grid (plain u32 counts)
//   [WIDE_N], [WIDE_N+1]        encoded running min / max
//   [PART_OFF, +NBLK*LWORDS)    per-block packed partial fine hists
#define MM_OFF   WIDE_N
#define PART_OFF (WIDE_N + 16)

typedef float f32x4 __attribute__((ext_vector_type(4)));

__device__ __forceinline__ unsigned enc_f32(float f) {
    unsigned u = __float_as_uint(f);
    return (u & 0x80000000u) ? ~u : (u | 0x80000000u);
}
__device__ __forceinline__ float dec_f32(unsigned e) {
    unsigned u = (e & 0x80000000u) ? (e ^ 0x80000000u) : ~e;
    return __uint_as_float(u);
}

__global__ void __launch_bounds__(256) hq_init(unsigned* ws) {
    long i = (long)blockIdx.x * blockDim.x + threadIdx.x;   // 1M threads
    ((uint4*)ws)[i] = make_uint4(0u, 0u, 0u, 0u);           // zero wide grid
    if (i == 0) {
        ws[MM_OFF]     = 0xFFFFFFFFu;  // min sentinel
        ws[MM_OFF + 1] = 0u;           // max sentinel
    }
}

__device__ __forceinline__ void fine_add(float c, float& vmin, float& vmax,
                                         unsigned* sh, unsigned* ws) {
    vmin = fminf(vmin, c);
    vmax = fmaxf(vmax, c);
    float t = floorf(c * 2048.0f);                 // EXACT: pow2 multiply
    t = fminf(fmaxf(t, -2097152.0f), 2097151.0f);  // clamp into wide grid
    int fi = (int)t;
    int li = fi + LHALF;
    if ((unsigned)li < (unsigned)LWIN) {
        atomicAdd(&sh[li >> 1], 1u << ((li & 1) << 4));  // packed 16-bit halves
    } else {
        atomicAdd(&ws[fi + WIDE_HALF], 1u);              // rare: |x| >= 4
    }
}

__global__ void __launch_bounds__(NTHR) hq_pass1(const f32x4* __restrict__ x4, long n4,
                                                 const float* __restrict__ xt, int ntail,
                                                 unsigned* __restrict__ ws) {
    __shared__ unsigned sh[LWORDS];
    __shared__ float smin[NTHR / 64], smax[NTHR / 64];
    for (int i = threadIdx.x; i < LWORDS; i += NTHR) sh[i] = 0u;
    __syncthreads();

    float vmin = INFINITY, vmax = -INFINITY;
    long i0 = (long)blockIdx.x * NTHR + threadIdx.x;
    long stride = (long)NBLK * NTHR;
    for (long i = i0; i < n4; i += stride) {
        f32x4 v = __builtin_nontemporal_load(&x4[i]);
        fine_add(v.x, vmin, vmax, sh, ws);
        fine_add(v.y, vmin, vmax, sh, ws);
        fine_add(v.z, vmin, vmax, sh, ws);
        fine_add(v.w, vmin, vmax, sh, ws);
    }
    if (blockIdx.x == 0 && threadIdx.x < ntail) {
        fine_add(xt[threadIdx.x], vmin, vmax, sh, ws);
    }

    #pragma unroll
    for (int off = 32; off; off >>= 1) {
        vmin = fminf(vmin, __shfl_xor(vmin, off));
        vmax = fmaxf(vmax, __shfl_xor(vmax, off));
    }
    int wid = threadIdx.x >> 6, lane = threadIdx.x & 63;
    if (lane == 0) { smin[wid] = vmin; smax[wid] = vmax; }
    __syncthreads();   // also fences all LDS hist atomics

    if (threadIdx.x == 0) {
        float bmin = INFINITY, bmax = -INFINITY;
        #pragma unroll
        for (int w = 0; w < NTHR / 64; ++w) {
            bmin = fminf(bmin, smin[w]);
            bmax = fmaxf(bmax, smax[w]);
        }
        atomicMin(&ws[MM_OFF], enc_f32(bmin));
        atomicMax(&ws[MM_OFF + 1], enc_f32(bmax));
    }

    unsigned* part = ws + PART_OFF + (size_t)blockIdx.x * LWORDS;
    for (int i = threadIdx.x; i < LWORDS; i += NTHR) part[i] = sh[i];
}

// Sum NBLK packed partials per word, unpack, merge into the wide grid.
// grid = 1024 blocks x 256: block -> (word chunk c of 256, partial group g of RGRP)
__global__ void __launch_bounds__(256) hq_reduce(unsigned* __restrict__ ws) {
    int c = blockIdx.x & 31;          // 32 chunks of 256 words = 8192
    int g = blockIdx.x >> 5;          // 32 groups of RGRP partials
    int w = c * 256 + threadIdx.x;    // packed word index in [0, LWORDS)
    const unsigned* p = ws + PART_OFF + w + (size_t)g * RGRP * LWORDS;
    unsigned slo = 0, shi = 0;
    #pragma unroll 8
    for (int b = 0; b < RGRP; ++b) {
        unsigned v = p[(size_t)b * LWORDS];
        slo += v & 0xFFFFu;
        shi += v >> 16;
    }
    unsigned base = WIDE_HALF - LHALF + 2 * w;
    if (slo) atomicAdd(&ws[base],     slo);
    if (shi) atomicAdd(&ws[base + 1], shi);
}

__global__ void __launch_bounds__(1024) hq_finalize(float* __restrict__ out,
                                                    const float* __restrict__ old_hist,
                                                    const float* __restrict__ min_val,
                                                    const float* __restrict__ max_val,
                                                    const unsigned* __restrict__ ws) {
    __shared__ float h[BINS];
    __shared__ float sc[2][BINS];
    int t = threadIdx.x;  // 1024 threads, 2 bins each

    float mn = min_val[0], mx = max_val[0];
    float cmin  = fminf(dec_f32(ws[MM_OFF]), mn);
    float cmax0 = fmaxf(dec_f32(ws[MM_OFF + 1]), mx);

    h[t]        = old_hist[t];
    h[t + 1024] = old_hist[t + 1024];
    sc[0][t]        = h[t];
    sc[0][t + 1024] = h[t + 1024];
    __syncthreads();

    // Hillis-Steele inclusive scan over 2048 elements
    int src = 0;
    for (int off = 1; off < BINS; off <<= 1) {
        int dst = src ^ 1;
        #pragma unroll
        for (int k = 0; k < 2; ++k) {
            int i = t + k * 1024;
            float v = sc[src][i];
            if (i >= off) v += sc[src][i - off];
            sc[dst][i] = v;
        }
        __syncthreads();
        src = dst;
    }
    const float* incl = sc[src];

    float hbw = (mx - mn) / (float)(BINS * UPSAMPLE);
    float bw  = (float)BINS * hbw;
    float dr_f = ceilf((cmax0 - cmin) / bw);
    float cmax = cmax0 + (dr_f * bw - (cmax0 - cmin));
    float hmn = truncf(cmin), hmx = truncf(cmax);   // integer-valued
    int dr = (int)dr_f;
    int start_idx = (int)rintf((mn - cmin) / hbw);  // round-half-even = jnp.round
    bool same = (cmin == mn) && (cmax == mx);
    int hmn_i = (int)hmn;
    int range_i = (int)(hmx - hmn);

    #pragma unroll
    for (int k = 0; k < 2; ++k) {
        int i = t + k * 1024;

        // hist_new[i]: sum of range_i fine bins starting at this bin's edge
        float hn = 0.0f;
        if (range_i > 0) {
            long fi0 = (long)hmn_i * 2048 + (long)i * range_i + WIDE_HALF;
            unsigned s = 0;
            for (int r = 0; r < range_i; ++r) {
                long fi = fi0 + r;
                if (fi >= 0 && fi < (long)WIDE_N) s += ws[fi];
            }
            hn = (float)s;
        }

        // analytic combine of the old histogram
        float integ_i = 0.0f, integ_p = 0.0f;
        {
            int q = (i + 1) * dr - 1 - start_idx;
            if (q >= 0) {
                int qc = min(q, BINS * UPSAMPLE - 1);
                int j = qc >> 7;
                float pref = (j ? incl[j - 1] : 0.0f) * (float)UPSAMPLE;
                integ_i = pref + ((float)(qc & 127) + 1.0f) * h[j];
            }
        }
        if (i > 0) {
            int q = i * dr - 1 - start_idx;
            if (q >= 0) {
                int qc = min(q, BINS * UPSAMPLE - 1);
                int j = qc >> 7;
                float pref = (j ? incl[j - 1] : 0.0f) * (float)UPSAMPLE;
                integ_p = pref + ((float)(qc & 127) + 1.0f) * h[j];
            }
        }
        float interp = (integ_i - integ_p) * (1.0f / (float)UPSAMPLE);
        out[i] = hn + (same ? h[i] : interp);
    }
    if (t == 0) {
        out[BINS]     = cmin;
        out[BINS + 1] = cmax;
    }
}

extern "C" void kernel_launch(void* const* d_in, const int* in_sizes, int n_in,
                              void* d_out, int out_size, void* d_ws, size_t ws_size,
                              hipStream_t stream) {
    (void)n_in; (void)out_size; (void)ws_size;
    const float* x         = (const float*)d_in[0];
    const float* histogram = (const float*)d_in[1];
    const float* min_val   = (const float*)d_in[2];
    const float* max_val   = (const float*)d_in[3];
    float* out   = (float*)d_out;
    unsigned* ws = (unsigned*)d_ws;

    long n  = (long)in_sizes[0];
    long n4 = n >> 2;
    int ntail = (int)(n & 3);
    const float* xt = x + (n4 << 2);

    hq_init<<<WIDE_N / 4 / 256, 256, 0, stream>>>(ws);
    hq_pass1<<<NBLK, NTHR, 0, stream>>>((const f32x4*)x, n4, xt, ntail, ws);
    hq_reduce<<<32 * RGRP, 256, 0, stream>>>(ws);
    hq_finalize<<<1, 1024, 0, stream>>>(out, histogram, min_val, max_val, ws);
}